// Round 4
// baseline (1158.193 us; speedup 1.0000x reference)
//
#include <hip/hip_runtime.h>

// out = Z + ((P@Z)@M @ (Z^T @ (Q@Z))) / N ; M[r,c]=0.9^(r-c) lower-tri (r,c<4096)
// bf16 MFMA GEMMs, matrices padded 4097->4352 (17*256) stride; K-loop trimmed to
// 4224 (66 tiles of 64; cols 4097..4223 are zeros).
// Grid-tail fix: tiles 0..255 full-K; tiles 256..288 split-K (dual: 2-way,
// singles: 4-way) into f32 partials + reduce kernel.
// Dual grid = 512 full + 2*33*2 tail = 644 blocks (round-3 bug: was 776 -> OOB).
// Chain: b0=Pb,b3=Qb,b1=Zt ; dual{PZ->b2, QZ->dox} ; reduce_dual ;
//        QZt=T(dox)->b3 ; left=scan(b2)->b0 ; rightT=gemm(b3,b1)->b2 (+reduce) ;
//        out = Z + gemm(b0,b2)/4096 (+reduce)

typedef __attribute__((ext_vector_type(8))) short short8;
typedef __attribute__((ext_vector_type(4))) float f32x4;
typedef __attribute__((ext_vector_type(4))) unsigned short u16x4;

#define NPAD 4352   // row stride, 17*256
#define NV   4097
#define NCTX 4096
#define NT   66     // K-tiles of 64 actually iterated (K=4224 >= 4097)

__device__ __forceinline__ float b2f(unsigned short u) {
  return __uint_as_float(((unsigned)u) << 16);
}
__device__ __forceinline__ unsigned short f2b(float f) {
  unsigned b = __float_as_uint(f);
  return (unsigned short)((b + 0x7FFFu + ((b >> 16) & 1u)) >> 16);
}
__device__ __forceinline__ void gload16(const void* g, void* l) {
  __builtin_amdgcn_global_load_lds(
      (const __attribute__((address_space(1))) unsigned int*)g,
      (__attribute__((address_space(3))) unsigned int*)l, 16, 0, 0);
}

// ---------------- cast + zero-pad: f32 [4097x4097] -> bf16 [4352x4352] --------
__global__ __launch_bounds__(256) void cast_pad(const float* __restrict__ in,
                                                unsigned short* __restrict__ out) {
  int idx = blockIdx.x * 256 + threadIdx.x;  // 4352 * 1088 quads
  int r = idx / 1088;
  int c4 = (idx - r * 1088) * 4;
  u16x4 o = {0, 0, 0, 0};
  if (r < NV) {
    const float* p = in + (size_t)r * NV + c4;
#pragma unroll
    for (int j = 0; j < 4; ++j) {
      float v = (c4 + j < NV) ? p[j] : 0.f;
      o[j] = f2b(v);
    }
  }
  *(u16x4*)&out[(size_t)r * NPAD + c4] = o;
}

// ------------- transpose-cast: f32 [4097x4097] -> bf16^T [4352x4352] ----------
__global__ __launch_bounds__(256) void transpose_cast(const float* __restrict__ in,
                                                      unsigned short* __restrict__ out) {
  __shared__ float tile[32][33];
  int x = threadIdx.x & 31;
  int y = threadIdx.x >> 5;
  int bx = blockIdx.x, by = blockIdx.y;
  int ic = bx * 32 + x;
#pragma unroll
  for (int j = 0; j < 4; ++j) {
    int ir = by * 32 + y + j * 8;
    float v = (ir < NV && ic < NV) ? in[(size_t)ir * NV + ic] : 0.f;
    tile[y + j * 8][x] = v;
  }
  __syncthreads();
  int orow = bx * 32;
  int ocol = by * 32 + x;
#pragma unroll
  for (int j = 0; j < 4; ++j) {
    out[(size_t)(orow + y + j * 8) * NPAD + ocol] = f2b(tile[x][y + j * 8]);
  }
}

// ------------- transpose bf16 [4352x4352] ------------------------------------
__global__ __launch_bounds__(256) void transpose_b16(const unsigned short* __restrict__ in,
                                                     unsigned short* __restrict__ out) {
  __shared__ unsigned short tile[32][33];
  int x = threadIdx.x & 31;
  int y = threadIdx.x >> 5;
  int bx = blockIdx.x, by = blockIdx.y;
  int ic = bx * 32 + x;
#pragma unroll
  for (int j = 0; j < 4; ++j) {
    int ir = by * 32 + y + j * 8;
    tile[y + j * 8][x] = in[(size_t)ir * NPAD + ic];
  }
  __syncthreads();
  int orow = bx * 32;
  int ocol = by * 32 + x;
#pragma unroll
  for (int j = 0; j < 4; ++j) {
    out[(size_t)(orow + y + j * 8) * NPAD + ocol] = tile[x][y + j * 8];
  }
}

// ------------- decay scan: left[:,c] = sum_{r>=c}^{4095} 0.9^(r-c) PZ[:,r] ----
__global__ __launch_bounds__(256) void decay_scan(const unsigned short* __restrict__ PZ,
                                                  unsigned short* __restrict__ L) {
  const int wid = (blockIdx.x << 2) | ((int)threadIdx.x >> 6);
  const int lane = threadIdx.x & 63;
  const int row = wid / 68;
  const int cj = wid - row * 68;
  const int c0 = cj * 64;

  const float l2l = -0.15200309344504995f;  // log2(0.9)
  const float pl = exp2f((float)lane * l2l);
  const float plc = exp2f((float)(64 - lane) * l2l);

  const unsigned short* prow = PZ + (size_t)row * NPAD;
  float x[5];
#pragma unroll
  for (int d = 0; d < 5; ++d) {
    int c = c0 + d * 64 + lane;
    x[d] = (c < NCTX) ? b2f(prow[c]) : 0.f;
  }
  float s = x[0];
  const float pw[6] = {0.9f, 0.81f, 0.6561f, 0.43046721f,
                       0.18530201888518410f, 0.03433683820292512f};
#pragma unroll
  for (int i = 0; i < 6; ++i) {
    int tt = 1 << i;
    float o = __shfl_down(s, tt);
    s += (lane + tt < 64) ? pw[i] * o : 0.f;
  }
  const float cw[4] = {1.f, 1.1790184577738583e-3f, 1.3900845237714557e-6f,
                       1.6389541800e-9f};
  float carry = 0.f;
#pragma unroll
  for (int d = 1; d <= 4; ++d) {
    float v = x[d] * pl;
#pragma unroll
    for (int i = 0; i < 6; ++i) v += __shfl_xor(v, 1 << i);
    carry += cw[d - 1] * v;
  }
  float left = s + plc * carry;
  L[(size_t)row * NPAD + c0 + lane] = f2b(left);
}

// ------------- 256x256 8-phase bf16 GEMM: C = A @ Bt^T ------------------------
// MODE 0: dual batch (nwg=644: 512 full + 2x33x2 split-K2 tail)
// MODE 1: single bf16 out (nwg=388: 256 full + 33x4 split-K4 tail)
// MODE 2: single f32 out = Zin + acc/4096 (same grid as MODE 1)
template <int MODE>
__global__ __launch_bounds__(512, 2) void gemm256(
    const unsigned short* __restrict__ A, const unsigned short* __restrict__ Bt,
    unsigned short* __restrict__ Cb, float* __restrict__ Cf,
    const float* __restrict__ Zin,
    const unsigned short* __restrict__ A2, unsigned short* __restrict__ Cb2,
    float* __restrict__ part0, float* __restrict__ part1, int nwg) {
  __shared__ __align__(16) unsigned short Asm[2][256 * 64];
  __shared__ __align__(16) unsigned short Bsm[2][256 * 64];

  const int tid = threadIdx.x;
  const int lane = tid & 63;
  const int w = tid >> 6;
  const int wr = w >> 2, wc = w & 3;
  const int q = lane >> 4, r16 = lane & 15;

  // bijective XCD swizzle (m204)
  int orig = blockIdx.x;
  int qq = nwg >> 3, rr8 = nwg & 7;
  int xcd = orig & 7, idx = orig >> 3;
  int wg = (xcd < rr8 ? xcd * (qq + 1) : rr8 * (qq + 1) + (xcd - rr8) * qq) + idx;

  // role: full-K tile or split-K tail-tile partial
  int tile, kb, ke;
  const unsigned short* Am = A;
  unsigned short* Co = Cb;
  float* Pp = nullptr;
  if (MODE == 0) {
    if (wg < 512) {
      int batch = wg >> 8;
      tile = wg & 255; kb = 0; ke = NT;
      Am = batch ? A2 : A; Co = batch ? Cb2 : Cb;
    } else {
      int e = wg - 512;                 // e in [0,132)
      int batch = (e >= 66) ? 1 : 0;
      int slot = e - batch * 66;        // slot in [0,66) = tile*2 + khalf
      tile = 256 + (slot >> 1);
      int kh = slot & 1;
      kb = kh * 33; ke = kb + 33;
      Am = batch ? A2 : A;
      Pp = (batch ? part1 : part0) + (size_t)slot * 65536;
    }
  } else {
    if (wg < 256) {
      tile = wg; kb = 0; ke = NT;
    } else {
      int e = wg - 256;                 // e in [0,132)
      tile = 256 + (e >> 2);
      int kq = e & 3;
      kb = kq * 16 + (kq < 2 ? kq : 2); // 17,17,16,16 split of 66
      ke = kb + (kq < 2 ? 17 : 16);
      Pp = part0 + (size_t)e * 65536;
    }
  }
  const int by = tile / 17, bx = tile - by * 17;
  const int brow = by * 256, bcol = bx * 256;

  // staging: linear LDS dest (global_load_lds), inverse-swizzled global source.
  auto stageA = [&](int ktile, int mq, int bb) {
#pragma unroll
    for (int it = 0; it < 2; ++it) {
      int sub = w * 16 + it * 8;
      int row0 = mq * 64 + sub + (sub & 64);
      int row = row0 + (lane >> 3);
      int win = (lane & 7) ^ (row & 7);
      gload16(Am + (size_t)(brow + row) * NPAD + ktile * 64 + win * 8,
              &Asm[bb][row0 * 64]);
    }
  };
  auto stageB = [&](int ktile, int nq, int bb) {
#pragma unroll
    for (int it = 0; it < 2; ++it) {
      int sub = w * 16 + it * 8;
      int row0 = ((sub >> 5) << 6) + nq * 32 + (sub & 31);
      int row = row0 + (lane >> 3);
      int win = (lane & 7) ^ (row & 7);
      gload16(Bt + (size_t)(bcol + row) * NPAD + ktile * 64 + win * 8,
              &Bsm[bb][row0 * 64]);
    }
  };

  short8 a[4][2], b0r[2][2], b1r[2][2];
  auto rdA = [&](int mq, int bb) {
#pragma unroll
    for (int m = 0; m < 4; ++m) {
      int row = wr * 128 + mq * 64 + m * 16 + r16;
#pragma unroll
      for (int kk = 0; kk < 2; ++kk) {
        int win = (q + kk * 4) ^ (r16 & 7);
        a[m][kk] = *(const short8*)&Asm[bb][row * 64 + win * 8];
      }
    }
  };
  auto rdB = [&](short8 (&b)[2][2], int nq, int bb) {
#pragma unroll
    for (int n = 0; n < 2; ++n) {
      int row = wc * 64 + nq * 32 + n * 16 + r16;
#pragma unroll
      for (int kk = 0; kk < 2; ++kk) {
        int win = (q + kk * 4) ^ (r16 & 7);
        b[n][kk] = *(const short8*)&Bsm[bb][row * 64 + win * 8];
      }
    }
  };

  f32x4 acc[8][4] = {};

  auto mma = [&](short8 (&b)[2][2], int mq, int nq) {
    __builtin_amdgcn_s_setprio(1);
#pragma unroll
    for (int kk = 0; kk < 2; ++kk)
#pragma unroll
      for (int m = 0; m < 4; ++m)
#pragma unroll
        for (int n = 0; n < 2; ++n)
          acc[mq * 4 + m][nq * 2 + n] = __builtin_amdgcn_mfma_f32_16x16x32_bf16(
              a[m][kk], b[n][kk], acc[mq * 4 + m][nq * 2 + n], 0, 0, 0);
    __builtin_amdgcn_s_setprio(0);
  };

  // prologue: tile kb fully -> buf0 ; tile kb+1 {A0,B0} -> buf1 ; drain kb.
  stageA(kb, 0, 0); stageB(kb, 0, 0); stageA(kb, 1, 0); stageB(kb, 1, 0);
  stageA(kb + 1, 0, 1); stageB(kb + 1, 0, 1);
  asm volatile("s_waitcnt vmcnt(4)" ::: "memory");
  __builtin_amdgcn_s_barrier();

  for (int kt = kb; kt < ke; ++kt) {
    const int bb = (kt - kb) & 1;
    rdA(0, bb);
    rdB(b0r, 0, bb);
    if (kt + 1 < ke) { stageA(kt + 1, 1, bb ^ 1); stageB(kt + 1, 1, bb ^ 1); }
    __builtin_amdgcn_s_barrier();
    mma(b0r, 0, 0);
    __builtin_amdgcn_s_barrier();
    rdB(b1r, 1, bb);
    __builtin_amdgcn_s_barrier();
    mma(b1r, 0, 1);
    __builtin_amdgcn_s_barrier();
    rdA(1, bb);
    if (kt + 2 < ke) stageA(kt + 2, 0, bb);
    __builtin_amdgcn_s_barrier();
    mma(b0r, 1, 0);
    __builtin_amdgcn_s_barrier();
    if (kt + 2 < ke) stageB(kt + 2, 0, bb);
    if (kt < ke - 2) { asm volatile("s_waitcnt vmcnt(4)" ::: "memory"); }
    else             { asm volatile("s_waitcnt vmcnt(0)" ::: "memory"); }
    __builtin_amdgcn_s_barrier();
    mma(b1r, 1, 1);
    __builtin_amdgcn_s_barrier();
  }

  if (Pp) {  // split-K partial: f32 tile-local [256][256]
#pragma unroll
    for (int m = 0; m < 8; ++m) {
      const int lr0 = wr * 128 + m * 16 + q * 4;
#pragma unroll
      for (int n = 0; n < 4; ++n) {
        const int lc = wc * 64 + n * 16 + r16;
#pragma unroll
        for (int v = 0; v < 4; ++v) Pp[(size_t)(lr0 + v) * 256 + lc] = acc[m][n][v];
      }
    }
  } else {
#pragma unroll
    for (int m = 0; m < 8; ++m) {
      const int row = brow + wr * 128 + m * 16 + q * 4;
#pragma unroll
      for (int n = 0; n < 4; ++n) {
        const int col = bcol + wc * 64 + n * 16 + r16;
#pragma unroll
        for (int v = 0; v < 4; ++v) {
          float val = acc[m][n][v];
          if (MODE == 2) {
            int rg = row + v;
            if (rg < NV && col < NV) {
              size_t o = (size_t)rg * NV + col;
              Cf[o] = Zin[o] + val * (1.0f / 4096.0f);
            }
          } else {
            Co[(size_t)(row + v) * NPAD + col] = f2b(val);
          }
        }
      }
    }
  }
}

// ------------- reduces for split-K tail tiles (tiles 256..288 of 17x17) -------
__global__ __launch_bounds__(256) void reduce_dual(const float* __restrict__ p0,
                                                   const float* __restrict__ p1,
                                                   unsigned short* __restrict__ C0,
                                                   unsigned short* __restrict__ C1) {
  int idx = (blockIdx.x * 256 + threadIdx.x) * 4;   // over 2*33*65536
  const int per = 33 * 65536;
  int b = idx >= per;
  int e = idx - b * per;
  int ti = e >> 16, j = e & 65535;
  const float* p = (b ? p1 : p0) + (size_t)(ti * 2) * 65536 + j;
  f32x4 s0 = *(const f32x4*)p;
  f32x4 s1 = *(const f32x4*)(p + 65536);
  int t = 256 + ti;
  int by = t / 17, bx = t - by * 17;
  unsigned short* C = b ? C1 : C0;
  u16x4 o;
#pragma unroll
  for (int v = 0; v < 4; ++v) o[v] = f2b(s0[v] + s1[v]);
  *(u16x4*)&C[(size_t)(by * 256 + (j >> 8)) * NPAD + bx * 256 + (j & 255)] = o;
}

template <int OM>  // 0: bf16 store; 1: f32 out = Z + s/4096 (valid region)
__global__ __launch_bounds__(256) void reduce_single(const float* __restrict__ p,
                                                     unsigned short* __restrict__ Cb,
                                                     float* __restrict__ Cf,
                                                     const float* __restrict__ Zin) {
  int idx = (blockIdx.x * 256 + threadIdx.x) * 4;   // over 33*65536
  int ti = idx >> 16, j = idx & 65535;
  const float* pp = p + (size_t)(ti * 4) * 65536 + j;
  f32x4 s = *(const f32x4*)pp;
#pragma unroll
  for (int kq = 1; kq < 4; ++kq) {
    f32x4 t = *(const f32x4*)(pp + (size_t)kq * 65536);
#pragma unroll
    for (int v = 0; v < 4; ++v) s[v] += t[v];
  }
  int t = 256 + ti;
  int by = t / 17, bx = t - by * 17;
  int row = by * 256 + (j >> 8);
  int col = bx * 256 + (j & 255);
  if (OM == 0) {
    u16x4 o;
#pragma unroll
    for (int v = 0; v < 4; ++v) o[v] = f2b(s[v]);
    *(u16x4*)&Cb[(size_t)row * NPAD + col] = o;
  } else {
    if (row < NV) {
#pragma unroll
      for (int v = 0; v < 4; ++v) {
        if (col + v < NV) {
          size_t o = (size_t)row * NV + col + v;
          Cf[o] = Zin[o] + s[v] * (1.0f / 4096.0f);
        }
      }
    }
  }
}

extern "C" void kernel_launch(void* const* d_in, const int* in_sizes, int n_in,
                              void* d_out, int out_size, void* d_ws, size_t ws_size,
                              hipStream_t stream) {
  (void)in_sizes; (void)n_in; (void)out_size; (void)ws_size;
  const float* Z = (const float*)d_in[0];
  const float* P = (const float*)d_in[1];
  const float* Q = (const float*)d_in[2];
  float* out = (float*)d_out;

  const size_t SZ = (size_t)NPAD * NPAD;
  unsigned short* b0 = (unsigned short*)d_ws;          // Pb -> left
  unsigned short* b1 = b0 + SZ;                        // Zt -> out-partials
  unsigned short* b2 = b1 + SZ;                        // PZ -> rightT
  unsigned short* b3 = b2 + SZ;                        // Qb -> QZt
  float* part_pz = (float*)(b3 + SZ);                  // 66*65536*4 = 17.3 MB (ws slack)
  unsigned short* dox = (unsigned short*)d_out;        // QZ bf16 (37.9 MB)
  float* part_qz = (float*)((char*)d_out + ((size_t)40 << 20));  // 17.3 MB in d_out tail
  float* part_rt = (float*)d_out;                      // 132*65536*4 = 34.6 MB (QZ dead)
  float* part_out = (float*)b1;                        // 34.6 MB (Zt dead)

  dim3 blk(256), blk5(512);
  dim3 gt(136, 136);

  cast_pad<<<18496, blk, 0, stream>>>(P, b0);
  cast_pad<<<18496, blk, 0, stream>>>(Q, b3);
  transpose_cast<<<gt, blk, 0, stream>>>(Z, b1);
  // dual: PZ = Pb@Z -> b2 ; QZ = Qb@Z -> dox (+ split-K2 tails)
  gemm256<0><<<644, blk5, 0, stream>>>(b0, b1, b2, nullptr, nullptr, b3, dox,
                                       part_pz, part_qz, 644);
  reduce_dual<<<4224, blk, 0, stream>>>(part_pz, part_qz, b2, dox);
  transpose_b16<<<gt, blk, 0, stream>>>(dox, b3);      // QZt
  decay_scan<<<73984, blk, 0, stream>>>(b2, b0);       // left
  // rightT = (QZ)^T @ Z = gemm(QZt, Zt) -> b2 (+ split-K4 tails -> d_out scratch)
  gemm256<1><<<388, blk5, 0, stream>>>(b3, b1, b2, nullptr, nullptr, nullptr, nullptr,
                                       part_rt, nullptr, 388);
  reduce_single<0><<<2112, blk, 0, stream>>>(part_rt, b2, nullptr, nullptr);
  // out = Z + gemm(left, rightT)/4096 (+ split-K4 tails -> b1 scratch)
  gemm256<2><<<388, blk5, 0, stream>>>(b0, b2, nullptr, out, Z, nullptr, nullptr,
                                       part_out, nullptr, 388);
  reduce_single<1><<<2112, blk, 0, stream>>>(part_out, nullptr, out, Z);
}

// Round 5
// 882.365 us; speedup vs baseline: 1.3126x; 1.3126x over previous
//
#include <hip/hip_runtime.h>

// out = Z + ((P@Z)@M @ (Z^T @ (Q@Z))) / N ; M[r,c]=0.9^(r-c) lower-tri (r,c<4096)
// bf16 MFMA GEMMs, matrices padded 4097->4352 (17*256) stride; K-loop = 65 tiles
// of 64 (4160 >= 4097; cols 4097..4159 zero).
// Grid packing (1 block/CU): full-K tiles first (XCD-swizzled within), split-K
// tail tiles LAST in launch order so shorts fill freed CUs:
//   dual:    512 full + 33x2x2-way-halfK  = 644 blocks  (~2.5 rounds)
//   singles: 256 full + 33x4-way-quarterK = 388 blocks  (~1.25 rounds)
// Chain: b0=Pb,b3=Qb,b1=Zt ; dual{PZ->b2, QZ->dox} ; reduce_dual ;
//        QZt=T(dox)->b3 ; left=scan(b2)->b0 ; rightT=gemm(b3,b1)->b2 (+reduce) ;
//        out = Z + gemm(b0,b2)/4096 (+reduce)

typedef __attribute__((ext_vector_type(8))) short short8;
typedef __attribute__((ext_vector_type(4))) float f32x4;
typedef __attribute__((ext_vector_type(4))) unsigned short u16x4;

#define NPAD 4352   // row stride, 17*256
#define NV   4097
#define NCTX 4096
#define NT   65     // K-tiles of 64 iterated (K=4160 >= 4097)

__device__ __forceinline__ float b2f(unsigned short u) {
  return __uint_as_float(((unsigned)u) << 16);
}
__device__ __forceinline__ unsigned short f2b(float f) {
  unsigned b = __float_as_uint(f);
  return (unsigned short)((b + 0x7FFFu + ((b >> 16) & 1u)) >> 16);
}
__device__ __forceinline__ void gload16(const void* g, void* l) {
  __builtin_amdgcn_global_load_lds(
      (const __attribute__((address_space(1))) unsigned int*)g,
      (__attribute__((address_space(3))) unsigned int*)l, 16, 0, 0);
}

// ---------------- cast + zero-pad: f32 [4097x4097] -> bf16 [4352x4352] --------
__global__ __launch_bounds__(256) void cast_pad(const float* __restrict__ in,
                                                unsigned short* __restrict__ out) {
  int idx = blockIdx.x * 256 + threadIdx.x;  // 4352 * 1088 quads
  int r = idx / 1088;
  int c4 = (idx - r * 1088) * 4;
  u16x4 o = {0, 0, 0, 0};
  if (r < NV) {
    const float* p = in + (size_t)r * NV + c4;
#pragma unroll
    for (int j = 0; j < 4; ++j) {
      float v = (c4 + j < NV) ? p[j] : 0.f;
      o[j] = f2b(v);
    }
  }
  *(u16x4*)&out[(size_t)r * NPAD + c4] = o;
}

// ------------- transpose-cast: f32 [4097x4097] -> bf16^T [4352x4352] ----------
__global__ __launch_bounds__(256) void transpose_cast(const float* __restrict__ in,
                                                      unsigned short* __restrict__ out) {
  __shared__ float tile[32][33];
  int x = threadIdx.x & 31;
  int y = threadIdx.x >> 5;
  int bx = blockIdx.x, by = blockIdx.y;
  int ic = bx * 32 + x;
#pragma unroll
  for (int j = 0; j < 4; ++j) {
    int ir = by * 32 + y + j * 8;
    float v = (ir < NV && ic < NV) ? in[(size_t)ir * NV + ic] : 0.f;
    tile[y + j * 8][x] = v;
  }
  __syncthreads();
  int orow = bx * 32;
  int ocol = by * 32 + x;
#pragma unroll
  for (int j = 0; j < 4; ++j) {
    out[(size_t)(orow + y + j * 8) * NPAD + ocol] = f2b(tile[x][y + j * 8]);
  }
}

// ------------- transpose bf16 [4352x4352] ------------------------------------
__global__ __launch_bounds__(256) void transpose_b16(const unsigned short* __restrict__ in,
                                                     unsigned short* __restrict__ out) {
  __shared__ unsigned short tile[32][33];
  int x = threadIdx.x & 31;
  int y = threadIdx.x >> 5;
  int bx = blockIdx.x, by = blockIdx.y;
  int ic = bx * 32 + x;
#pragma unroll
  for (int j = 0; j < 4; ++j) {
    int ir = by * 32 + y + j * 8;
    tile[y + j * 8][x] = in[(size_t)ir * NPAD + ic];
  }
  __syncthreads();
  int orow = bx * 32;
  int ocol = by * 32 + x;
#pragma unroll
  for (int j = 0; j < 4; ++j) {
    out[(size_t)(orow + y + j * 8) * NPAD + ocol] = tile[x][y + j * 8];
  }
}

// ------------- decay scan: left[:,c] = sum_{r>=c}^{4095} 0.9^(r-c) PZ[:,r] ----
__global__ __launch_bounds__(256) void decay_scan(const unsigned short* __restrict__ PZ,
                                                  unsigned short* __restrict__ L) {
  const int wid = (blockIdx.x << 2) | ((int)threadIdx.x >> 6);
  const int lane = threadIdx.x & 63;
  const int row = wid / 65;
  const int cj = wid - row * 65;
  const int c0 = cj * 64;

  const float l2l = -0.15200309344504995f;  // log2(0.9)
  const float pl = exp2f((float)lane * l2l);
  const float plc = exp2f((float)(64 - lane) * l2l);

  const unsigned short* prow = PZ + (size_t)row * NPAD;
  float x[5];
#pragma unroll
  for (int d = 0; d < 5; ++d) {
    int c = c0 + d * 64 + lane;
    x[d] = (c < NCTX) ? b2f(prow[c]) : 0.f;
  }
  float s = x[0];
  const float pw[6] = {0.9f, 0.81f, 0.6561f, 0.43046721f,
                       0.18530201888518410f, 0.03433683820292512f};
#pragma unroll
  for (int i = 0; i < 6; ++i) {
    int tt = 1 << i;
    float o = __shfl_down(s, tt);
    s += (lane + tt < 64) ? pw[i] * o : 0.f;
  }
  const float cw[4] = {1.f, 1.1790184577738583e-3f, 1.3900845237714557e-6f,
                       1.6389541800e-9f};
  float carry = 0.f;
#pragma unroll
  for (int d = 1; d <= 4; ++d) {
    float v = x[d] * pl;
#pragma unroll
    for (int i = 0; i < 6; ++i) v += __shfl_xor(v, 1 << i);
    carry += cw[d - 1] * v;
  }
  float left = s + plc * carry;
  L[(size_t)row * NPAD + c0 + lane] = f2b(left);
}

// ------------- 256x256 8-phase bf16 GEMM: C = A @ Bt^T ------------------------
// MODE 0: dual batch (644 blocks: 512 full + 132 half-K tail, tail LAST)
// MODE 1: single bf16 out (388 blocks: 256 full + 132 quarter-K tail, tail LAST)
// MODE 2: single f32 out = Zin + acc/4096 (same grid as MODE 1)
template <int MODE>
__global__ __launch_bounds__(512, 2) void gemm256(
    const unsigned short* __restrict__ A, const unsigned short* __restrict__ Bt,
    unsigned short* __restrict__ Cb, float* __restrict__ Cf,
    const float* __restrict__ Zin,
    const unsigned short* __restrict__ A2, unsigned short* __restrict__ Cb2,
    float* __restrict__ part0, float* __restrict__ part1) {
  __shared__ __align__(16) unsigned short Asm[2][256 * 64];
  __shared__ __align__(16) unsigned short Bsm[2][256 * 64];

  const int tid = threadIdx.x;
  const int lane = tid & 63;
  const int w = tid >> 6;
  const int wr = w >> 2, wc = w & 3;
  const int q = lane >> 4, r16 = lane & 15;

  // full-K blocks first (XCD-swizzled within; NFULL%8==0 so simple swizzle is
  // bijective); split-K tail blocks keep wg=orig -> launch LAST.
  const int NFULL = (MODE == 0) ? 512 : 256;
  int orig = blockIdx.x;
  int wg;
  if (orig < NFULL) {
    const int cpx = NFULL >> 3;
    wg = (orig & 7) * cpx + (orig >> 3);
  } else {
    wg = orig;
  }

  // role decode
  int tile, kb, ke;
  const unsigned short* Am = A;
  unsigned short* Co = Cb;
  float* Pp = nullptr;
  if (MODE == 0) {
    if (wg < 512) {
      int batch = wg >> 8;
      tile = wg & 255; kb = 0; ke = NT;
      Am = batch ? A2 : A; Co = batch ? Cb2 : Cb;
    } else {
      int e = wg - 512;                 // [0,132)
      int batch = (e >= 66) ? 1 : 0;
      int slot = e - batch * 66;        // [0,66) = tile_local*2 + khalf
      tile = 256 + (slot >> 1);
      int kh = slot & 1;
      kb = kh * 33; ke = kh ? NT : 33;  // 33 / 32 tiles
      Am = batch ? A2 : A;
      Pp = (batch ? part1 : part0) + (size_t)slot * 65536;
    }
  } else {
    if (wg < 256) {
      tile = wg; kb = 0; ke = NT;
    } else {
      int e = wg - 256;                 // [0,132)
      tile = 256 + (e >> 2);
      int kq = e & 3;
      kb = (kq == 0) ? 0 : 17 + 16 * (kq - 1);   // 0,17,33,49
      ke = kb + ((kq == 0) ? 17 : 16);           // 17/16/16/16 of 65
      Pp = part0 + (size_t)e * 65536;
    }
  }
  const int by = tile / 17, bx = tile - by * 17;
  const int brow = by * 256, bcol = bx * 256;

  // staging: linear LDS dest (global_load_lds), inverse-swizzled global source.
  auto stageA = [&](int ktile, int mq, int bb) {
#pragma unroll
    for (int it = 0; it < 2; ++it) {
      int sub = w * 16 + it * 8;
      int row0 = mq * 64 + sub + (sub & 64);
      int row = row0 + (lane >> 3);
      int win = (lane & 7) ^ (row & 7);
      gload16(Am + (size_t)(brow + row) * NPAD + ktile * 64 + win * 8,
              &Asm[bb][row0 * 64]);
    }
  };
  auto stageB = [&](int ktile, int nq, int bb) {
#pragma unroll
    for (int it = 0; it < 2; ++it) {
      int sub = w * 16 + it * 8;
      int row0 = ((sub >> 5) << 6) + nq * 32 + (sub & 31);
      int row = row0 + (lane >> 3);
      int win = (lane & 7) ^ (row & 7);
      gload16(Bt + (size_t)(bcol + row) * NPAD + ktile * 64 + win * 8,
              &Bsm[bb][row0 * 64]);
    }
  };

  short8 a[4][2], b0r[2][2], b1r[2][2];
  auto rdA = [&](int mq, int bb) {
#pragma unroll
    for (int m = 0; m < 4; ++m) {
      int row = wr * 128 + mq * 64 + m * 16 + r16;
#pragma unroll
      for (int kk = 0; kk < 2; ++kk) {
        int win = (q + kk * 4) ^ (r16 & 7);
        a[m][kk] = *(const short8*)&Asm[bb][row * 64 + win * 8];
      }
    }
  };
  auto rdB = [&](short8 (&b)[2][2], int nq, int bb) {
#pragma unroll
    for (int n = 0; n < 2; ++n) {
      int row = wc * 64 + nq * 32 + n * 16 + r16;
#pragma unroll
      for (int kk = 0; kk < 2; ++kk) {
        int win = (q + kk * 4) ^ (r16 & 7);
        b[n][kk] = *(const short8*)&Bsm[bb][row * 64 + win * 8];
      }
    }
  };

  f32x4 acc[8][4] = {};

  auto mma = [&](short8 (&b)[2][2], int mq, int nq) {
    __builtin_amdgcn_s_setprio(1);
#pragma unroll
    for (int kk = 0; kk < 2; ++kk)
#pragma unroll
      for (int m = 0; m < 4; ++m)
#pragma unroll
        for (int n = 0; n < 2; ++n)
          acc[mq * 4 + m][nq * 2 + n] = __builtin_amdgcn_mfma_f32_16x16x32_bf16(
              a[m][kk], b[n][kk], acc[mq * 4 + m][nq * 2 + n], 0, 0, 0);
    __builtin_amdgcn_s_setprio(0);
  };

  // prologue: tile kb fully -> buf0 ; tile kb+1 {A0,B0} -> buf1 ; drain kb.
  stageA(kb, 0, 0); stageB(kb, 0, 0); stageA(kb, 1, 0); stageB(kb, 1, 0);
  stageA(kb + 1, 0, 1); stageB(kb + 1, 0, 1);
  asm volatile("s_waitcnt vmcnt(4)" ::: "memory");
  __builtin_amdgcn_s_barrier();

  for (int kt = kb; kt < ke; ++kt) {
    const int bb = (kt - kb) & 1;
    rdA(0, bb);
    rdB(b0r, 0, bb);
    if (kt + 1 < ke) { stageA(kt + 1, 1, bb ^ 1); stageB(kt + 1, 1, bb ^ 1); }
    __builtin_amdgcn_s_barrier();
    mma(b0r, 0, 0);
    __builtin_amdgcn_s_barrier();
    rdB(b1r, 1, bb);
    __builtin_amdgcn_s_barrier();
    mma(b1r, 0, 1);
    __builtin_amdgcn_s_barrier();
    rdA(1, bb);
    if (kt + 2 < ke) stageA(kt + 2, 0, bb);
    __builtin_amdgcn_s_barrier();
    mma(b0r, 1, 0);
    __builtin_amdgcn_s_barrier();
    if (kt + 2 < ke) stageB(kt + 2, 0, bb);
    if (kt < ke - 2) { asm volatile("s_waitcnt vmcnt(4)" ::: "memory"); }
    else             { asm volatile("s_waitcnt vmcnt(0)" ::: "memory"); }
    __builtin_amdgcn_s_barrier();
    mma(b1r, 1, 1);
    __builtin_amdgcn_s_barrier();
  }

  if (Pp) {  // split-K partial: f32 tile-local [256][256]
#pragma unroll
    for (int m = 0; m < 8; ++m) {
      const int lr0 = wr * 128 + m * 16 + q * 4;
#pragma unroll
      for (int n = 0; n < 4; ++n) {
        const int lc = wc * 64 + n * 16 + r16;
#pragma unroll
        for (int v = 0; v < 4; ++v) Pp[(size_t)(lr0 + v) * 256 + lc] = acc[m][n][v];
      }
    }
  } else {
#pragma unroll
    for (int m = 0; m < 8; ++m) {
      const int row = brow + wr * 128 + m * 16 + q * 4;
#pragma unroll
      for (int n = 0; n < 4; ++n) {
        const int col = bcol + wc * 64 + n * 16 + r16;
#pragma unroll
        for (int v = 0; v < 4; ++v) {
          float val = acc[m][n][v];
          if (MODE == 2) {
            int rg = row + v;
            if (rg < NV && col < NV) {
              size_t o = (size_t)rg * NV + col;
              Cf[o] = Zin[o] + val * (1.0f / 4096.0f);
            }
          } else {
            Co[(size_t)(row + v) * NPAD + col] = f2b(val);
          }
        }
      }
    }
  }
}

// ------------- reduces for split-K tail tiles (tiles 256..288 of 17x17) -------
__global__ __launch_bounds__(256) void reduce_dual(const float* __restrict__ p0,
                                                   const float* __restrict__ p1,
                                                   unsigned short* __restrict__ C0,
                                                   unsigned short* __restrict__ C1) {
  int idx = (blockIdx.x * 256 + threadIdx.x) * 4;   // over 2*33*65536
  const int per = 33 * 65536;
  int b = idx >= per;
  int e = idx - b * per;
  int ti = e >> 16, j = e & 65535;
  const float* p = (b ? p1 : p0) + (size_t)(ti * 2) * 65536 + j;
  f32x4 s0 = *(const f32x4*)p;
  f32x4 s1 = *(const f32x4*)(p + 65536);
  int t = 256 + ti;
  int by = t / 17, bx = t - by * 17;
  unsigned short* C = b ? C1 : C0;
  u16x4 o;
#pragma unroll
  for (int v = 0; v < 4; ++v) o[v] = f2b(s0[v] + s1[v]);
  *(u16x4*)&C[(size_t)(by * 256 + (j >> 8)) * NPAD + bx * 256 + (j & 255)] = o;
}

template <int OM>  // 0: bf16 store; 1: f32 out = Z + s/4096 (valid region)
__global__ __launch_bounds__(256) void reduce_single(const float* __restrict__ p,
                                                     unsigned short* __restrict__ Cb,
                                                     float* __restrict__ Cf,
                                                     const float* __restrict__ Zin) {
  int idx = (blockIdx.x * 256 + threadIdx.x) * 4;   // over 33*65536
  int ti = idx >> 16, j = idx & 65535;
  const float* pp = p + (size_t)(ti * 4) * 65536 + j;
  f32x4 s = *(const f32x4*)pp;
#pragma unroll
  for (int kq = 1; kq < 4; ++kq) {
    f32x4 t = *(const f32x4*)(pp + (size_t)kq * 65536);
#pragma unroll
    for (int v = 0; v < 4; ++v) s[v] += t[v];
  }
  int t = 256 + ti;
  int by = t / 17, bx = t - by * 17;
  int row = by * 256 + (j >> 8);
  int col = bx * 256 + (j & 255);
  if (OM == 0) {
    u16x4 o;
#pragma unroll
    for (int v = 0; v < 4; ++v) o[v] = f2b(s[v]);
    *(u16x4*)&Cb[(size_t)row * NPAD + col] = o;
  } else {
    if (row < NV) {
#pragma unroll
      for (int v = 0; v < 4; ++v) {
        if (col + v < NV) {
          size_t o = (size_t)row * NV + col + v;
          Cf[o] = Zin[o] + s[v] * (1.0f / 4096.0f);
        }
      }
    }
  }
}

extern "C" void kernel_launch(void* const* d_in, const int* in_sizes, int n_in,
                              void* d_out, int out_size, void* d_ws, size_t ws_size,
                              hipStream_t stream) {
  (void)in_sizes; (void)n_in; (void)out_size; (void)ws_size;
  const float* Z = (const float*)d_in[0];
  const float* P = (const float*)d_in[1];
  const float* Q = (const float*)d_in[2];
  float* out = (float*)d_out;

  const size_t SZ = (size_t)NPAD * NPAD;
  unsigned short* b0 = (unsigned short*)d_ws;          // Pb -> left
  unsigned short* b1 = b0 + SZ;                        // Zt -> out-partials
  unsigned short* b2 = b1 + SZ;                        // PZ -> rightT
  unsigned short* b3 = b2 + SZ;                        // Qb -> QZt
  float* part_pz = (float*)(b3 + SZ);                  // 66*65536*4 = 17.3 MB (ws slack)
  unsigned short* dox = (unsigned short*)d_out;        // QZ bf16 (37.9 MB)
  float* part_qz = (float*)((char*)d_out + ((size_t)40 << 20));  // 17.3 MB d_out tail
  float* part_rt = (float*)d_out;                      // 132*256KB = 34.6 MB (QZ dead)
  float* part_out = (float*)b1;                        // 34.6 MB (Zt dead)

  dim3 blk(256), blk5(512);
  dim3 gt(136, 136);

  cast_pad<<<18496, blk, 0, stream>>>(P, b0);
  cast_pad<<<18496, blk, 0, stream>>>(Q, b3);
  transpose_cast<<<gt, blk, 0, stream>>>(Z, b1);
  // dual: PZ = Pb@Z -> b2 ; QZ = Qb@Z -> dox (+ split-K2 tails)
  gemm256<0><<<644, blk5, 0, stream>>>(b0, b1, b2, nullptr, nullptr, b3, dox,
                                       part_pz, part_qz);
  reduce_dual<<<4224, blk, 0, stream>>>(part_pz, part_qz, b2, dox);
  transpose_b16<<<gt, blk, 0, stream>>>(dox, b3);      // QZt
  decay_scan<<<70720, blk, 0, stream>>>(b2, b0);       // left (4352 rows x 65 chunks)
  // rightT = (QZ)^T @ Z = gemm(QZt, Zt) -> b2 (+ split-K4 tails -> d_out scratch)
  gemm256<1><<<388, blk5, 0, stream>>>(b3, b1, b2, nullptr, nullptr, nullptr, nullptr,
                                       part_rt, nullptr);
  reduce_single<0><<<2112, blk, 0, stream>>>(part_rt, b2, nullptr, nullptr);
  // out = Z + gemm(left, rightT)/4096 (+ split-K4 tails -> b1 scratch)
  gemm256<2><<<388, blk5, 0, stream>>>(b0, b2, nullptr, out, Z, nullptr, nullptr,
                                       part_out, nullptr);
  reduce_single<1><<<2112, blk, 0, stream>>>(part_out, nullptr, out, Z);
}